// Round 1
// baseline (295.672 us; speedup 1.0000x reference)
//
#include <hip/hip_runtime.h>
#include <hip/hip_bf16.h>

typedef __attribute__((ext_vector_type(8))) short short8;
typedef __attribute__((ext_vector_type(4))) float f32x4;
typedef __attribute__((ext_vector_type(4))) unsigned int uint4v;

#define BM 128
#define BN 128
#define BK 64
#define DK 256   // K dimension (D) — fixed for this problem

// pack two fp32 into one dword of 2x bf16 (truncation; error budget is ~2%)
__device__ __forceinline__ unsigned int pack2bf(float lo, float hi) {
  unsigned int ulo = __builtin_bit_cast(unsigned int, lo);
  unsigned int uhi = __builtin_bit_cast(unsigned int, hi);
  // result = [hi16(uhi) : hi16(ulo)] ; v_perm pool: src1=bytes0-3, src0=bytes4-7
  return __builtin_amdgcn_perm(uhi, ulo, 0x07060302);
}

__global__ void __launch_bounds__(256)
centroid_gemm_pool(const float* __restrict__ x, const float* __restrict__ w,
                   const int* __restrict__ graph, float* __restrict__ outsum,
                   int N, int C, int row_tiles)
{
  __shared__ __align__(16) unsigned char lds_a[BM * BK * 2];
  __shared__ __align__(16) unsigned char lds_b[BN * BK * 2];
  __shared__ float xsq[BM];
  __shared__ float csq[BN];
  __shared__ float colsum[BN];
  __shared__ int g_loc[BM];

  // XCD-aware mapping: the 4 col-tiles of one row-tile land on the SAME XCD
  // (bids differing by 8 -> same XCD under round-robin dispatch) so the A
  // row-tile is read from HBM once, reused 4x out of that XCD's L2.
  const int bid = blockIdx.x;
  const int xcd = bid & 7;
  const int j   = bid >> 3;
  const int ct  = j & 3;                // col tile (C=512 -> 4 tiles of 128)
  const int rt  = (j >> 2) * 8 + xcd;   // row tile
  if (rt >= row_tiles) return;

  const int t    = threadIdx.x;
  const int lane = t & 63;
  const int wid  = t >> 6;
  const int wr   = wid >> 1;            // wave row (0..1): rows 64*wr..
  const int wc   = wid & 1;             // wave col (0..1): cols 64*wc..
  const int h    = lane >> 4;
  const int l15  = lane & 15;

  if (t < BM) {
    int rg = rt * BM + t;
    g_loc[t] = (rg < N) ? graph[rg] : -1;
  }

  f32x4 acc[4][4];
  #pragma unroll
  for (int m = 0; m < 4; ++m)
    #pragma unroll
    for (int n = 0; n < 4; ++n)
      acc[m][n] = (f32x4){0.f, 0.f, 0.f, 0.f};

  float sqa[4] = {0.f, 0.f, 0.f, 0.f};
  float sqb[4] = {0.f, 0.f, 0.f, 0.f};

  // staging map: thread t handles rows (t>>3)+32q, 8 contiguous floats at col (t&7)*8
  const int srow = t >> 3;
  const int scol = (t & 7) * 8;

  for (int kt = 0; kt < DK / BK; ++kt) {
    const int k0 = kt * BK;
    // ---- stage A (x) fp32 -> bf16, accumulate sum-of-squares ----
    #pragma unroll
    for (int q = 0; q < 4; ++q) {
      const int row  = srow + 32 * q;
      const int grow = rt * BM + row;
      f32x4 v0 = {0.f,0.f,0.f,0.f}, v1 = {0.f,0.f,0.f,0.f};
      if (grow < N) {
        const float* p = x + (size_t)grow * DK + (k0 + scol);
        v0 = *reinterpret_cast<const f32x4*>(p);
        v1 = *reinterpret_cast<const f32x4*>(p + 4);
      }
      sqa[q] += v0.x*v0.x + v0.y*v0.y + v0.z*v0.z + v0.w*v0.w
              + v1.x*v1.x + v1.y*v1.y + v1.z*v1.z + v1.w*v1.w;
      uint4v pk = { pack2bf(v0.x, v0.y), pack2bf(v0.z, v0.w),
                    pack2bf(v1.x, v1.y), pack2bf(v1.z, v1.w) };
      const int off = (row * (BK * 2) + (t & 7) * 16) ^ ((row & 7) << 4);
      *reinterpret_cast<uint4v*>(lds_a + off) = pk;
    }
    // ---- stage B (centroids); C=512 divisible by BN, no guard ----
    #pragma unroll
    for (int q = 0; q < 4; ++q) {
      const int row = srow + 32 * q;
      const float* p = w + (size_t)(ct * BN + row) * DK + (k0 + scol);
      f32x4 v0 = *reinterpret_cast<const f32x4*>(p);
      f32x4 v1 = *reinterpret_cast<const f32x4*>(p + 4);
      sqb[q] += v0.x*v0.x + v0.y*v0.y + v0.z*v0.z + v0.w*v0.w
              + v1.x*v1.x + v1.y*v1.y + v1.z*v1.z + v1.w*v1.w;
      uint4v pk = { pack2bf(v0.x, v0.y), pack2bf(v0.z, v0.w),
                    pack2bf(v1.x, v1.y), pack2bf(v1.z, v1.w) };
      const int off = (row * (BK * 2) + (t & 7) * 16) ^ ((row & 7) << 4);
      *reinterpret_cast<uint4v*>(lds_b + off) = pk;
    }
    __syncthreads();
    // ---- MFMA: 2 k-slices of 32, 16 mfma each ----
    #pragma unroll
    for (int kk = 0; kk < 2; ++kk) {
      short8 af[4], bfr[4];
      #pragma unroll
      for (int m = 0; m < 4; ++m) {
        const int row = wr * 64 + m * 16 + l15;
        const int off = (row * (BK * 2) + (kk * 4 + h) * 16) ^ ((row & 7) << 4);
        af[m] = *reinterpret_cast<const short8*>(lds_a + off);
      }
      #pragma unroll
      for (int n = 0; n < 4; ++n) {
        const int row = wc * 64 + n * 16 + l15;
        const int off = (row * (BK * 2) + (kk * 4 + h) * 16) ^ ((row & 7) << 4);
        bfr[n] = *reinterpret_cast<const short8*>(lds_b + off);
      }
      #pragma unroll
      for (int m = 0; m < 4; ++m)
        #pragma unroll
        for (int n = 0; n < 4; ++n)
          acc[m][n] = __builtin_amdgcn_mfma_f32_16x16x32_bf16(af[m], bfr[n], acc[m][n], 0, 0, 0);
    }
    __syncthreads();
  }

  // ---- reduce per-row / per-centroid squared norms (8 lanes share a row) ----
  #pragma unroll
  for (int q = 0; q < 4; ++q) {
    float s = sqa[q];
    s += __shfl_xor(s, 1); s += __shfl_xor(s, 2); s += __shfl_xor(s, 4);
    if ((t & 7) == 0) xsq[srow + 32 * q] = s;
    float sb = sqb[q];
    sb += __shfl_xor(sb, 1); sb += __shfl_xor(sb, 2); sb += __shfl_xor(sb, 4);
    if ((t & 7) == 0) csq[srow + 32 * q] = sb;
  }
  __syncthreads();

  // ---- dist = sqrt(max(xsq + csq - 2*dot, 0)) in-register ----
  float xs[4][4], cs[4];
  #pragma unroll
  for (int m = 0; m < 4; ++m)
    #pragma unroll
    for (int i = 0; i < 4; ++i)
      xs[m][i] = xsq[wr * 64 + m * 16 + h * 4 + i];
  #pragma unroll
  for (int n = 0; n < 4; ++n)
    cs[n] = csq[wc * 64 + n * 16 + l15];
  #pragma unroll
  for (int m = 0; m < 4; ++m)
    #pragma unroll
    for (int n = 0; n < 4; ++n)
      #pragma unroll
      for (int i = 0; i < 4; ++i) {
        float dd = xs[m][i] + cs[n] - 2.0f * acc[m][n][i];
        acc[m][n][i] = sqrtf(fmaxf(dd, 0.f));
      }

  // ---- segment reduction over sorted graph runs (typically 1-2 runs/block) ----
  int s0 = 0;
  while (s0 < BM) {
    const int g = g_loc[s0];
    int e = s0 + 1;
    while (e < BM && g_loc[e] == g) ++e;
    if (g >= 0) {
      float p[4] = {0.f, 0.f, 0.f, 0.f};
      #pragma unroll
      for (int m = 0; m < 4; ++m)
        #pragma unroll
        for (int i = 0; i < 4; ++i) {
          const int rl = wr * 64 + m * 16 + h * 4 + i;
          const bool in = (rl >= s0) && (rl < e);
          #pragma unroll
          for (int n = 0; n < 4; ++n)
            p[n] += in ? acc[m][n][i] : 0.f;
        }
      #pragma unroll
      for (int n = 0; n < 4; ++n) {
        p[n] += __shfl_xor(p[n], 16);
        p[n] += __shfl_xor(p[n], 32);
      }
      if (t < BN) colsum[t] = 0.f;
      __syncthreads();
      if (lane < 16) {
        #pragma unroll
        for (int n = 0; n < 4; ++n)
          atomicAdd(&colsum[wc * 64 + n * 16 + lane], p[n]);
      }
      __syncthreads();
      if (t < BN)
        atomicAdd(&outsum[(size_t)g * C + ct * BN + t], colsum[t]);
      __syncthreads();
    }
    s0 = e;
  }
}

// out[g][c] /= max(count(g),1); counts via binary search over the SORTED graph array
__global__ void __launch_bounds__(128)
divide_by_count(float* __restrict__ out, const int* __restrict__ graph, int N, int C)
{
  const int g = blockIdx.x;
  int lo = 0, hi = N;
  while (lo < hi) { int mid = (lo + hi) >> 1; if (graph[mid] < g) lo = mid + 1; else hi = mid; }
  const int lb = lo;
  hi = N;
  while (lo < hi) { int mid = (lo + hi) >> 1; if (graph[mid] <= g) lo = mid + 1; else hi = mid; }
  const int cnt = lo - lb;
  const float inv = 1.0f / (float)(cnt > 1 ? cnt : 1);
  for (int c = threadIdx.x; c < C; c += blockDim.x)
    out[(size_t)g * C + c] *= inv;
}

extern "C" void kernel_launch(void* const* d_in, const int* in_sizes, int n_in,
                              void* d_out, int out_size, void* d_ws, size_t ws_size,
                              hipStream_t stream) {
  const float* x     = (const float*)d_in[0];
  const float* w     = (const float*)d_in[1];
  const int*   graph = (const int*)d_in[2];
  const int N = in_sizes[2];                 // 200000
  const int D = in_sizes[0] / N;             // 256
  const int C = in_sizes[1] / D;             // 512
  const int G = out_size / C;                // 512

  const int row_tiles = (N + BM - 1) / BM;   // 1563
  const int rgroups   = (row_tiles + 7) / 8; // 196
  const int col_tiles = C / BN;              // 4

  hipMemsetAsync(d_out, 0, (size_t)out_size * sizeof(float), stream);
  centroid_gemm_pool<<<dim3(rgroups * 8 * col_tiles), dim3(256), 0, stream>>>(
      x, w, graph, (float*)d_out, N, C, row_tiles);
  divide_by_count<<<dim3(G), dim3(128), 0, stream>>>((float*)d_out, graph, N, C);
}

// Round 2
// 274.364 us; speedup vs baseline: 1.0777x; 1.0777x over previous
//
#include <hip/hip_runtime.h>
#include <hip/hip_bf16.h>

typedef __attribute__((ext_vector_type(8))) short short8;
typedef __attribute__((ext_vector_type(4))) float f32x4;
typedef __attribute__((ext_vector_type(4))) unsigned int uint4v;

#define BM 128
#define BN 128
#define BK 64
#define DK 256   // K dimension (D) — fixed for this problem

// pack two fp32 into one dword of 2x bf16 (truncation; error budget ~2% of |out|)
__device__ __forceinline__ unsigned int pack2bf(float lo, float hi) {
  unsigned int ulo = __builtin_bit_cast(unsigned int, lo);
  unsigned int uhi = __builtin_bit_cast(unsigned int, hi);
  return __builtin_amdgcn_perm(uhi, ulo, 0x07060302);
}

__global__ void __launch_bounds__(256)
centroid_gemm_pool(const float* __restrict__ x, const float* __restrict__ w,
                   const int* __restrict__ graph, float* __restrict__ outsum,
                   int N, int C, int row_tiles)
{
  __shared__ __align__(16) unsigned char lds_a[BM * BK * 2];
  __shared__ __align__(16) unsigned char lds_b[BN * BK * 2];
  __shared__ float xsq[BM];
  __shared__ float csq[BN];
  __shared__ float cpart[2][BN];
  __shared__ int g_loc[BM];
  __shared__ unsigned long long bmask[2];

  // XCD-aware mapping: the 4 col-tiles of one row-tile land on the SAME XCD
  // so the A row-tile is fetched from HBM once, reused 4x via that XCD's L2.
  const int bid = blockIdx.x;
  const int xcd = bid & 7;
  const int j   = bid >> 3;
  const int ct  = j & 3;                // col tile (C=512 -> 4 tiles of 128)
  const int rt  = (j >> 2) * 8 + xcd;   // row tile
  if (rt >= row_tiles) return;

  const int t    = threadIdx.x;
  const int lane = t & 63;
  const int wid  = t >> 6;
  const int wr   = wid >> 1;            // wave row (0..1)
  const int wc   = wid & 1;             // wave col (0..1)
  const int h    = lane >> 4;
  const int l15  = lane & 15;

  if (t < BM) {
    int rg = rt * BM + t;
    g_loc[t] = (rg < N) ? graph[rg] : -1;
  }

  f32x4 acc[4][4];
  #pragma unroll
  for (int m = 0; m < 4; ++m)
    #pragma unroll
    for (int n = 0; n < 4; ++n)
      acc[m][n] = (f32x4){0.f, 0.f, 0.f, 0.f};

  float sqa[4] = {0.f, 0.f, 0.f, 0.f};
  float sqb[4] = {0.f, 0.f, 0.f, 0.f};

  // staging map: thread t handles rows (t>>3)+32q, 8 contiguous floats at col (t&7)*8
  const int srow = t >> 3;
  const int scol = (t & 7) * 8;

  // kt-invariant pointers; OOB rows clamp to N-1 (finite garbage, masked in epilogue)
  const float* aptr[4];
  #pragma unroll
  for (int q = 0; q < 4; ++q) {
    int grow = rt * BM + srow + 32 * q;
    if (grow >= N) grow = N - 1;
    aptr[q] = x + (size_t)grow * DK + scol;
  }
  const float* bptr = w + (size_t)(ct * BN + srow) * DK + scol;

  // kt-invariant LDS write offset; rows srow+32q share (row&7)==(srow&7)
  const int wlo = (srow * (BK * 2) + (t & 7) * 16) ^ ((srow & 7) << 4);

  // ---- software pipeline: prefetch A (HBM) one K-step ahead ----
  f32x4 ra0[4], ra1[4];
  auto load_a = [&](int kt) {
    #pragma unroll
    for (int q = 0; q < 4; ++q) {
      ra0[q] = *reinterpret_cast<const f32x4*>(aptr[q] + kt * BK);
      ra1[q] = *reinterpret_cast<const f32x4*>(aptr[q] + kt * BK + 4);
    }
  };
  load_a(0);

  #pragma unroll
  for (int kt = 0; kt < DK / BK; ++kt) {
    // ---- stage B (centroids; L2-resident, synchronous) ----
    #pragma unroll
    for (int q = 0; q < 4; ++q) {
      const float* p = bptr + (size_t)q * 32 * DK + kt * BK;
      f32x4 v0 = *reinterpret_cast<const f32x4*>(p);
      f32x4 v1 = *reinterpret_cast<const f32x4*>(p + 4);
      sqb[q] += v0.x*v0.x + v0.y*v0.y + v0.z*v0.z + v0.w*v0.w
              + v1.x*v1.x + v1.y*v1.y + v1.z*v1.z + v1.w*v1.w;
      uint4v pk = { pack2bf(v0.x, v0.y), pack2bf(v0.z, v0.w),
                    pack2bf(v1.x, v1.y), pack2bf(v1.z, v1.w) };
      *reinterpret_cast<uint4v*>(lds_b + wlo + q * 4096) = pk;
    }
    // ---- consume prefetched A, convert + write LDS ----
    #pragma unroll
    for (int q = 0; q < 4; ++q) {
      f32x4 v0 = ra0[q], v1 = ra1[q];
      sqa[q] += v0.x*v0.x + v0.y*v0.y + v0.z*v0.z + v0.w*v0.w
              + v1.x*v1.x + v1.y*v1.y + v1.z*v1.z + v1.w*v1.w;
      uint4v pk = { pack2bf(v0.x, v0.y), pack2bf(v0.z, v0.w),
                    pack2bf(v1.x, v1.y), pack2bf(v1.z, v1.w) };
      *reinterpret_cast<uint4v*>(lds_a + wlo + q * 4096) = pk;
    }
    // issue next K-step's A loads NOW — they stay in flight across the raw
    // barrier (no vmcnt drain) and hide under the MFMA phase.
    if (kt < DK / BK - 1) load_a(kt + 1);

    asm volatile("s_waitcnt lgkmcnt(0)" ::: "memory");
    __builtin_amdgcn_s_barrier();
    __builtin_amdgcn_sched_barrier(0);

    // ---- MFMA: 2 k-slices of 32, 16 mfma each ----
    #pragma unroll
    for (int kk = 0; kk < 2; ++kk) {
      short8 af[4], bfr[4];
      #pragma unroll
      for (int m = 0; m < 4; ++m) {
        const int row = wr * 64 + m * 16 + l15;
        const int off = (row * (BK * 2) + (kk * 4 + h) * 16) ^ ((row & 7) << 4);
        af[m] = *reinterpret_cast<const short8*>(lds_a + off);
      }
      #pragma unroll
      for (int n = 0; n < 4; ++n) {
        const int row = wc * 64 + n * 16 + l15;
        const int off = (row * (BK * 2) + (kk * 4 + h) * 16) ^ ((row & 7) << 4);
        bfr[n] = *reinterpret_cast<const short8*>(lds_b + off);
      }
      #pragma unroll
      for (int m = 0; m < 4; ++m)
        #pragma unroll
        for (int n = 0; n < 4; ++n)
          acc[m][n] = __builtin_amdgcn_mfma_f32_16x16x32_bf16(af[m], bfr[n], acc[m][n], 0, 0, 0);
    }
    asm volatile("s_waitcnt lgkmcnt(0)" ::: "memory");
    __builtin_amdgcn_s_barrier();
    __builtin_amdgcn_sched_barrier(0);
  }

  // ---- per-row / per-centroid squared norms (8 lanes share a row) ----
  #pragma unroll
  for (int q = 0; q < 4; ++q) {
    float s = sqa[q];
    s += __shfl_xor(s, 1); s += __shfl_xor(s, 2); s += __shfl_xor(s, 4);
    if ((t & 7) == 0) xsq[srow + 32 * q] = s;
    float sb = sqb[q];
    sb += __shfl_xor(sb, 1); sb += __shfl_xor(sb, 2); sb += __shfl_xor(sb, 4);
    if ((t & 7) == 0) csq[srow + 32 * q] = sb;
  }
  // run boundaries via ballot (rows 0..127 live in waves 0-1)
  if (t < BM) {
    bool b = (t == 0) || (g_loc[t] != g_loc[t - 1]);
    unsigned long long m = __ballot(b);
    if ((t & 63) == 0) bmask[t >> 6] = m;
  }
  __syncthreads();

  // ---- dist = sqrt(max(xsq + csq - 2*dot, 0)) in-register ----
  float xs[4][4], cs[4];
  #pragma unroll
  for (int m = 0; m < 4; ++m)
    #pragma unroll
    for (int i = 0; i < 4; ++i)
      xs[m][i] = xsq[wr * 64 + m * 16 + h * 4 + i];
  #pragma unroll
  for (int n = 0; n < 4; ++n)
    cs[n] = csq[wc * 64 + n * 16 + l15];
  #pragma unroll
  for (int m = 0; m < 4; ++m)
    #pragma unroll
    for (int n = 0; n < 4; ++n)
      #pragma unroll
      for (int i = 0; i < 4; ++i) {
        float dd = xs[m][i] + cs[n] - 2.0f * acc[m][n][i];
        acc[m][n][i] = sqrtf(fmaxf(dd, 0.f));
      }

  // ---- segment reduction: iterate runs from the register-resident bit mask ----
  const unsigned long long w0 = bmask[0], w1 = bmask[1];
  int s0 = 0;
  while (s0 < BM) {
    const int g = g_loc[s0];
    int e;
    if (s0 < 63 && (w0 >> (s0 + 1)) != 0ULL)
      e = s0 + 1 + __builtin_ctzll(w0 >> (s0 + 1));
    else if (s0 < 64)
      e = w1 ? 64 + __builtin_ctzll(w1) : BM;
    else if (s0 < BM - 1 && (w1 >> (s0 - 63)) != 0ULL)
      e = s0 + 1 + __builtin_ctzll(w1 >> (s0 - 63));
    else
      e = BM;
    if (g >= 0) {
      float p[4] = {0.f, 0.f, 0.f, 0.f};
      #pragma unroll
      for (int m = 0; m < 4; ++m)
        #pragma unroll
        for (int i = 0; i < 4; ++i) {
          const int rl = wr * 64 + m * 16 + h * 4 + i;
          const bool in = (rl >= s0) && (rl < e);
          #pragma unroll
          for (int n = 0; n < 4; ++n)
            p[n] += in ? acc[m][n][i] : 0.f;
        }
      #pragma unroll
      for (int n = 0; n < 4; ++n) {
        p[n] += __shfl_xor(p[n], 16);
        p[n] += __shfl_xor(p[n], 32);
      }
      if (lane < 16) {
        #pragma unroll
        for (int n = 0; n < 4; ++n)
          cpart[wr][wc * 64 + n * 16 + lane] = p[n];
      }
      __syncthreads();
      if (t < BN)
        atomicAdd(&outsum[(size_t)g * C + ct * BN + t], cpart[0][t] + cpart[1][t]);
      __syncthreads();
    }
    s0 = e;
  }
}

// out[g][c] /= max(count(g),1); counts via binary search over the SORTED graph array
__global__ void __launch_bounds__(128)
divide_by_count(float* __restrict__ out, const int* __restrict__ graph, int N, int C)
{
  const int g = blockIdx.x;
  int lo = 0, hi = N;
  while (lo < hi) { int mid = (lo + hi) >> 1; if (graph[mid] < g) lo = mid + 1; else hi = mid; }
  const int lb = lo;
  hi = N;
  while (lo < hi) { int mid = (lo + hi) >> 1; if (graph[mid] <= g) lo = mid + 1; else hi = mid; }
  const int cnt = lo - lb;
  const float inv = 1.0f / (float)(cnt > 1 ? cnt : 1);
  for (int c = threadIdx.x; c < C; c += blockDim.x)
    out[(size_t)g * C + c] *= inv;
}

extern "C" void kernel_launch(void* const* d_in, const int* in_sizes, int n_in,
                              void* d_out, int out_size, void* d_ws, size_t ws_size,
                              hipStream_t stream) {
  const float* x     = (const float*)d_in[0];
  const float* w     = (const float*)d_in[1];
  const int*   graph = (const int*)d_in[2];
  const int N = in_sizes[2];                 // 200000
  const int D = in_sizes[0] / N;             // 256
  const int C = in_sizes[1] / D;             // 512
  const int G = out_size / C;                // 512

  const int row_tiles = (N + BM - 1) / BM;   // 1563
  const int rgroups   = (row_tiles + 7) / 8; // 196
  const int col_tiles = C / BN;              // 4

  hipMemsetAsync(d_out, 0, (size_t)out_size * sizeof(float), stream);
  centroid_gemm_pool<<<dim3(rgroups * 8 * col_tiles), dim3(256), 0, stream>>>(
      x, w, graph, (float*)d_out, N, C, row_tiles);
  divide_by_count<<<dim3(G), dim3(128), 0, stream>>>((float*)d_out, graph, N, C);
}

// Round 3
// 161.138 us; speedup vs baseline: 1.8349x; 1.7027x over previous
//
#include <hip/hip_runtime.h>
#include <hip/hip_bf16.h>

typedef __attribute__((ext_vector_type(8))) short short8;
typedef __attribute__((ext_vector_type(4))) float f32x4;
typedef __attribute__((ext_vector_type(4))) unsigned int uint4v;

#define DK 256   // K dimension (D) — fixed
#define BM 256   // rows per block (4 waves x 64 rows)
#define BN 128   // cols per block (C=512 -> 4 col tiles)

// pack two fp32 into one dword of 2x bf16 (truncation; error budget ~2% of |out|)
__device__ __forceinline__ unsigned int pack2bf(float lo, float hi) {
  unsigned int ulo = __builtin_bit_cast(unsigned int, lo);
  unsigned int uhi = __builtin_bit_cast(unsigned int, hi);
  return __builtin_amdgcn_perm(uhi, ulo, 0x07060302);
}

__global__ void __launch_bounds__(256, 2)
centroid_gemm_pool(const float* __restrict__ x, const float* __restrict__ w,
                   const int* __restrict__ graph, float* __restrict__ outsum,
                   int* __restrict__ cnt, int N, int C, int row_groups)
{
  // B tile resident for the whole block: [128 cols][256 k] bf16, XOR-swizzled
  __shared__ __align__(16) unsigned char lds_b[BN * DK * 2];   // 64 KB
  __shared__ float csq_lds[BN];

  // XCD grouping: the 4 col-tiles of one row-group land on the SAME XCD
  // (bids differing by 8/16/24 -> same bid&7) so x rows are L2-served 3 of 4 times.
  const int bid = blockIdx.x;
  const int xcd = bid & 7;
  const int j   = bid >> 3;
  const int ct  = j & 3;               // col tile
  const int rg  = (j >> 2) * 8 + xcd;  // row group
  if (rg >= row_groups) return;

  const int t    = threadIdx.x;
  const int lane = t & 63;
  const int wid  = t >> 6;
  const int h    = lane >> 4;
  const int l15  = lane & 15;

  // ---- stage B once: fp32 -> bf16 -> swizzled LDS; csq in fp32 ----
  {
    const int col   = t >> 1;
    const int khalf = t & 1;
    const float* gp = w + (size_t)(ct * BN + col) * DK + khalf * 128;
    unsigned char* base = lds_b + col * 512 + khalf * 256;
    const int sw = (col & 15) << 4;
    float cq = 0.f;
    #pragma unroll
    for (int jj = 0; jj < 16; ++jj) {
      f32x4 v0 = *reinterpret_cast<const f32x4*>(gp + jj * 8);
      f32x4 v1 = *reinterpret_cast<const f32x4*>(gp + jj * 8 + 4);
      cq += v0.x*v0.x + v0.y*v0.y + v0.z*v0.z + v0.w*v0.w
          + v1.x*v1.x + v1.y*v1.y + v1.z*v1.z + v1.w*v1.w;
      uint4v pk = { pack2bf(v0.x,v0.y), pack2bf(v0.z,v0.w),
                    pack2bf(v1.x,v1.y), pack2bf(v1.z,v1.w) };
      *reinterpret_cast<uint4v*>(base + ((jj * 16) ^ sw)) = pk;
    }
    cq += __shfl_xor(cq, 1);
    if (khalf == 0) csq_lds[col] = cq;
  }
  __syncthreads();
  // ---- from here on, waves are fully independent (no more block barriers) ----

  const int wbase = rg * BM + wid * 64;   // this wave's 64 rows

  // k-invariant per-mt row pointers (A frag: row = mt*16 + l15, k = h*8 + ...)
  const float* ap[4];
  #pragma unroll
  for (int mt = 0; mt < 4; ++mt) {
    int r = wbase + mt * 16 + l15;
    if (r > N - 1) r = N - 1;             // clamp; garbage rows masked later
    ap[mt] = x + (size_t)r * DK + h * 8;
  }

  // B LDS read base: col = nt*16 + l15 -> sw = l15<<4 split into h-bits / ks-bits
  const int bbase = l15 * 512 + ((h * 16) ^ ((l15 << 4) & 0x30));
  const int sxor  = (l15 << 4) & 0xC0;

  f32x4 acc[4][8];
  #pragma unroll
  for (int mt = 0; mt < 4; ++mt)
    #pragma unroll
    for (int nt = 0; nt < 8; ++nt)
      acc[mt][nt] = (f32x4){0.f, 0.f, 0.f, 0.f};
  float xq[4] = {0.f, 0.f, 0.f, 0.f};

  f32x4 a0[4], a1[4];
  #pragma unroll
  for (int mt = 0; mt < 4; ++mt) {
    a0[mt] = *reinterpret_cast<const f32x4*>(ap[mt]);
    a1[mt] = *reinterpret_cast<const f32x4*>(ap[mt] + 4);
  }

  #pragma unroll
  for (int ks = 0; ks < 8; ++ks) {
    short8 af[4];
    #pragma unroll
    for (int mt = 0; mt < 4; ++mt) {
      f32x4 v0 = a0[mt], v1 = a1[mt];
      xq[mt] += v0.x*v0.x + v0.y*v0.y + v0.z*v0.z + v0.w*v0.w
              + v1.x*v1.x + v1.y*v1.y + v1.z*v1.z + v1.w*v1.w;
      uint4v pk = { pack2bf(v0.x,v0.y), pack2bf(v0.z,v0.w),
                    pack2bf(v1.x,v1.y), pack2bf(v1.z,v1.w) };
      af[mt] = __builtin_bit_cast(short8, pk);
    }
    if (ks < 7) {
      #pragma unroll
      for (int mt = 0; mt < 4; ++mt) {
        a0[mt] = *reinterpret_cast<const f32x4*>(ap[mt] + (ks + 1) * 32);
        a1[mt] = *reinterpret_cast<const f32x4*>(ap[mt] + (ks + 1) * 32 + 4);
      }
    }
    const int koff = ((ks * 64) ^ sxor);
    #pragma unroll
    for (int nt = 0; nt < 8; ++nt) {
      short8 bf = *reinterpret_cast<const short8*>(lds_b + bbase + koff + nt * 8192);
      #pragma unroll
      for (int mt = 0; mt < 4; ++mt)
        acc[mt][nt] = __builtin_amdgcn_mfma_f32_16x16x32_bf16(af[mt], bf, acc[mt][nt], 0, 0, 0);
    }
  }

  // ---- finish xsq: sum the 4 h-group partials, then redistribute per acc row ----
  #pragma unroll
  for (int mt = 0; mt < 4; ++mt) {
    xq[mt] += __shfl_xor(xq[mt], 16);
    xq[mt] += __shfl_xor(xq[mt], 32);
  }
  float xs[4][4];
  #pragma unroll
  for (int mt = 0; mt < 4; ++mt)
    #pragma unroll
    for (int i = 0; i < 4; ++i)
      xs[mt][i] = __shfl(xq[mt], h * 4 + i);   // value lives at lane l15 == h*4+i
  float cs[8];
  #pragma unroll
  for (int nt = 0; nt < 8; ++nt)
    cs[nt] = csq_lds[nt * 16 + l15];

  // ---- dist = sqrt(max(xsq + csq - 2*dot, 0)) ----
  #pragma unroll
  for (int mt = 0; mt < 4; ++mt)
    #pragma unroll
    for (int nt = 0; nt < 8; ++nt)
      #pragma unroll
      for (int i = 0; i < 4; ++i) {
        float dd = fmaf(-2.0f, acc[mt][nt][i], xs[mt][i] + cs[nt]);
        acc[mt][nt][i] = __builtin_amdgcn_sqrtf(fmaxf(dd, 0.f));
      }

  // ---- wave-local segment reduction over sorted runs ----
  const int rowg = wbase + lane;
  const int gl   = (rowg < N) ? graph[rowg] : -1;
  const int glp  = __shfl_up(gl, 1);
  const unsigned long long bm = __ballot(lane == 0 || gl != glp);

  int s0 = 0;
  while (s0 < 64) {
    unsigned long long rest = (s0 < 63) ? (bm >> (s0 + 1)) : 0ULL;
    const int e = rest ? s0 + 1 + __builtin_ctzll(rest) : 64;
    const int g = __shfl(gl, s0);
    if (g >= 0) {
      float p[8] = {0.f,0.f,0.f,0.f,0.f,0.f,0.f,0.f};
      #pragma unroll
      for (int mt = 0; mt < 4; ++mt)
        #pragma unroll
        for (int i = 0; i < 4; ++i) {
          const int row = mt * 16 + h * 4 + i;
          const bool in = (row >= s0) && (row < e);
          #pragma unroll
          for (int nt = 0; nt < 8; ++nt)
            p[nt] += in ? acc[mt][nt][i] : 0.f;
        }
      #pragma unroll
      for (int nt = 0; nt < 8; ++nt) {
        p[nt] += __shfl_xor(p[nt], 16);
        p[nt] += __shfl_xor(p[nt], 32);
      }
      if (lane < 16) {
        #pragma unroll
        for (int nt = 0; nt < 8; ++nt)
          atomicAdd(&outsum[(size_t)g * C + ct * BN + nt * 16 + lane], p[nt]);
      }
      if (cnt && ct == 0 && lane == 0)
        atomicAdd(&cnt[g], e - s0);
    }
    s0 = e;
  }
}

__global__ void __launch_bounds__(256)
divide_counts(float* __restrict__ out, const int* __restrict__ cnt, int C)
{
  const int g = blockIdx.x;
  const int c0 = cnt[g];
  const float inv = 1.0f / (float)(c0 > 1 ? c0 : 1);
  for (int c = threadIdx.x; c < C; c += 256)
    out[(size_t)g * C + c] *= inv;
}

// fallback if d_ws is too small: counts via binary search over the sorted graph
__global__ void __launch_bounds__(128)
divide_by_count(float* __restrict__ out, const int* __restrict__ graph, int N, int C)
{
  const int g = blockIdx.x;
  int lo = 0, hi = N;
  while (lo < hi) { int mid = (lo + hi) >> 1; if (graph[mid] < g) lo = mid + 1; else hi = mid; }
  const int lb = lo;
  hi = N;
  while (lo < hi) { int mid = (lo + hi) >> 1; if (graph[mid] <= g) lo = mid + 1; else hi = mid; }
  const int cntg = lo - lb;
  const float inv = 1.0f / (float)(cntg > 1 ? cntg : 1);
  for (int c = threadIdx.x; c < C; c += blockDim.x)
    out[(size_t)g * C + c] *= inv;
}

extern "C" void kernel_launch(void* const* d_in, const int* in_sizes, int n_in,
                              void* d_out, int out_size, void* d_ws, size_t ws_size,
                              hipStream_t stream) {
  const float* x     = (const float*)d_in[0];
  const float* w     = (const float*)d_in[1];
  const int*   graph = (const int*)d_in[2];
  const int N = in_sizes[2];                 // 200000
  const int D = in_sizes[0] / N;             // 256
  const int C = in_sizes[1] / D;             // 512
  const int G = out_size / C;                // 512

  const int row_groups = (N + BM - 1) / BM;  // 782
  const int rg8 = (row_groups + 7) / 8;      // 98

  const bool use_ws = ws_size >= (size_t)G * sizeof(int);

  hipMemsetAsync(d_out, 0, (size_t)out_size * sizeof(float), stream);
  if (use_ws) hipMemsetAsync(d_ws, 0, (size_t)G * sizeof(int), stream);

  centroid_gemm_pool<<<dim3(rg8 * 8 * 4), dim3(256), 0, stream>>>(
      x, w, graph, (float*)d_out, use_ws ? (int*)d_ws : nullptr, N, C, row_groups);

  if (use_ws)
    divide_counts<<<dim3(G), dim3(256), 0, stream>>>((float*)d_out, (const int*)d_ws, C);
  else
    divide_by_count<<<dim3(G), dim3(128), 0, stream>>>((float*)d_out, graph, N, C);
}